// Round 17
// baseline (93.799 us; speedup 1.0000x reference)
//
#include <hip/hip_runtime.h>
#include <hip/hip_bf16.h>
#include <hip/hip_fp8.h>

typedef float f32x16 __attribute__((ext_vector_type(16)));

constexpr int NROW = 8192;
constexpr int DCOL = 256;                  // row length in elements (= bytes in fp8)
constexpr int BM = 128;
constexpr int BKB = 128;                   // K-slab bytes (full 8-chunk swizzle period)
constexpr int NT = NROW / BM;              // 64
constexpr int NTILES = NT * (NT + 1) / 2;  // 2080 (divisible by 8)
constexpr float MARGIN = 0.3f;

// async global->LDS, 16B per lane; LDS dest is wave-uniform base (HW adds lane*16)
__device__ inline void gload16(const unsigned char* g, unsigned char* l) {
    __builtin_amdgcn_global_load_lds(
        (const __attribute__((address_space(1))) void*)g,
        (__attribute__((address_space(3))) void*)l, 16, 0, 0);
}

// ---------------- normalize rows -> fp8 e4m3; zero completion counter ----------------
__global__ __launch_bounds__(256) void normalize_kernel(const float* __restrict__ hidden,
                                                        unsigned char* __restrict__ xn,
                                                        unsigned int* __restrict__ counter) {
    if (blockIdx.x == 0 && threadIdx.x == 0) counter[0] = 0u;
    int wid = threadIdx.x >> 6, lane = threadIdx.x & 63;
    int row = (blockIdx.x << 2) + wid;
    const float4* src = reinterpret_cast<const float4*>(hidden + (size_t)row * DCOL);
    float4 v = src[lane];
    float ss = v.x * v.x + v.y * v.y + v.z * v.z + v.w * v.w;
    #pragma unroll
    for (int off = 32; off; off >>= 1) ss += __shfl_down(ss, off);
    ss = __shfl(ss, 0);
    float inv = 1.0f / fmaxf(sqrtf(ss), 1e-8f);
    __hip_fp8_e4m3 q0(v.x * inv), q1(v.y * inv), q2(v.z * inv), q3(v.w * inv);
    uchar4 o;
    o.x = *reinterpret_cast<unsigned char*>(&q0);
    o.y = *reinterpret_cast<unsigned char*>(&q1);
    o.z = *reinterpret_cast<unsigned char*>(&q2);
    o.w = *reinterpret_cast<unsigned char*>(&q3);
    reinterpret_cast<uchar4*>(xn + (size_t)row * DCOL)[lane] = o;
}

// ---------------- 128x128-tile, 4-wave fp8 MFMA Gram + fused pair loss + fused finalize ----
// r16 core (4 blocks/CU = 4 waves/SIMD, the proven occupancy lever). New: last-finishing
// block performs the final reduction (agent-scope partials + completion counter) ->
// third kernel and its launch gap eliminated. Fixed-order tree reduce = deterministic.
__global__ __launch_bounds__(256) void pairloss_kernel(const unsigned char* __restrict__ xn,
                                                       const int* __restrict__ labels,
                                                       float* __restrict__ partials,
                                                       unsigned int* __restrict__ counter,
                                                       float* __restrict__ out) {
    __shared__ unsigned char As[BM * BKB];      // 16KB, one K-slab
    __shared__ unsigned char Bs[BM * BKB];      // 16KB
    __shared__ int lblA[BM], lblB[BM];
    __shared__ float wsum[4];
    __shared__ int lastFlag;

    // XCD-aware bijective swizzle
    int bid = (int)(blockIdx.x & 7) * (NTILES / 8) + (int)(blockIdx.x >> 3);
    int bi = 0, rem = bid;
    while (rem >= NT - bi) { rem -= NT - bi; ++bi; }
    int bj = bi + rem;

    int tid = threadIdx.x;
    int wid = tid >> 6, lane = tid & 63;
    int wr = wid >> 1, wc = wid & 1;            // 2x2 waves, wave tile 64x64
    int brow = bi * BM, bcol = bj * BM;

    if (tid < BM) lblA[tid] = labels[brow + tid];
    else          lblB[tid - BM] = labels[bcol + tid - BM];

    f32x16 acc[2][2] = {};                      // 2x2 tiles of 32x32 per wave

    int srow = lane >> 3;                       // row within 8-row group
    int schunk = (lane & 7) ^ srow;             // pre-swizzled 16B source chunk (r&7 == srow)
    const unsigned char* gA0 = xn + (size_t)brow * DCOL;
    const unsigned char* gB0 = xn + (size_t)bcol * DCOL;
    int lo = lane & 31, hi = lane >> 5;

    auto stage = [&](int s) {                   // 8 VMEM instr/thread per slab
        #pragma unroll
        for (int q = 0; q < 4; ++q) {
            int rg = (wid * 4 + q) * 8;         // wave-uniform 8-row group
            int goff = (rg + srow) * DCOL + s * BKB + schunk * 16;
            gload16(gA0 + goff, &As[rg * BKB]); // 8 rows x 128B, linear dest
            gload16(gB0 + goff, &Bs[rg * BKB]);
        }
    };
    auto compute = [&]() {
        #pragma unroll
        for (int kk = 0; kk < 8; ++kk) {        // K16 sub-steps of BKB=128
            long af[2], bfr[2];                 // 8 fp8 = 2 VGPRs each
            #pragma unroll
            for (int m = 0; m < 2; ++m) {
                int r = wr * 64 + m * 32 + lo;  // r&7 == lane&7
                af[m] = *reinterpret_cast<const long*>(
                    &As[r * BKB + ((kk ^ (r & 7)) << 4) + hi * 8]);
            }
            #pragma unroll
            for (int n = 0; n < 2; ++n) {
                int r = wc * 64 + n * 32 + lo;
                bfr[n] = *reinterpret_cast<const long*>(
                    &Bs[r * BKB + ((kk ^ (r & 7)) << 4) + hi * 8]);
            }
            __builtin_amdgcn_s_setprio(1);
            #pragma unroll
            for (int m = 0; m < 2; ++m)
                #pragma unroll
                for (int n = 0; n < 2; ++n)
                    acc[m][n] = __builtin_amdgcn_mfma_f32_32x32x16_fp8_fp8(af[m], bfr[n], acc[m][n], 0, 0, 0);
            __builtin_amdgcn_s_setprio(0);
        }
    };

    stage(0);
    asm volatile("s_waitcnt vmcnt(0)" ::: "memory");
    __builtin_amdgcn_s_barrier();               // slab0 landed for all waves
    compute();
    __builtin_amdgcn_s_barrier();               // all readers done before overwrite
    stage(1);
    asm volatile("s_waitcnt vmcnt(0)" ::: "memory");
    __builtin_amdgcn_s_barrier();               // slab1 landed
    compute();

    // epilogue: per-pair loss, strict upper triangle
    // 32x32 C/D: col = lane&31, row = (reg&3) + 8*(reg>>2) + 4*(lane>>5)  (dtype-independent)
    float local = 0.0f;
    #pragma unroll
    for (int m = 0; m < 2; ++m) {
        #pragma unroll
        for (int n = 0; n < 2; ++n) {
            #pragma unroll
            for (int g = 0; g < 16; ++g) {
                int crow = (g & 3) + 8 * (g >> 2) + 4 * hi;
                int il = wr * 64 + m * 32 + crow;
                int jl = wc * 64 + n * 32 + lo;
                int gi = brow + il, gj = bcol + jl;
                float sim = acc[m][n][g];
                float v = (lblA[il] == lblB[jl]) ? (1.0f - sim) : fmaxf(sim - MARGIN, 0.0f);
                local += (gi < gj) ? v : 0.0f;
            }
        }
    }
    #pragma unroll
    for (int off = 32; off; off >>= 1) local += __shfl_down(local, off);
    if (lane == 0)                               // agent-visible per-wave partial
        __hip_atomic_store(&partials[bid * 4 + wid], local,
                           __ATOMIC_RELAXED, __HIP_MEMORY_SCOPE_AGENT);
    __syncthreads();
    if (tid == 0) {
        __threadfence();                         // partials visible before counter bump
        unsigned int c = __hip_atomic_fetch_add(counter, 1u,
                                                __ATOMIC_ACQ_REL, __HIP_MEMORY_SCOPE_AGENT);
        lastFlag = (c == (unsigned int)(NTILES - 1));
    }
    __syncthreads();
    if (lastFlag) {                              // last-finishing block: fused finalize
        float s = 0.0f;
        for (int i = tid; i < NTILES * 4; i += 256)
            s += __hip_atomic_load(&partials[i], __ATOMIC_RELAXED, __HIP_MEMORY_SCOPE_AGENT);
        #pragma unroll
        for (int off = 32; off; off >>= 1) s += __shfl_down(s, off);
        if (lane == 0) wsum[wid] = s;
        __syncthreads();
        if (tid == 0)
            out[0] = (wsum[0] + wsum[1] + wsum[2] + wsum[3]) * (1.0f / 33550336.0f);
    }
}

extern "C" void kernel_launch(void* const* d_in, const int* in_sizes, int n_in,
                              void* d_out, int out_size, void* d_ws, size_t ws_size,
                              hipStream_t stream) {
    const float* hidden = (const float*)d_in[0];
    const int* labels = (const int*)d_in[1];
    float* out = (float*)d_out;

    unsigned char* xn = (unsigned char*)d_ws;                                // 2 MB fp8
    float* partials = (float*)((char*)d_ws + (size_t)NROW * DCOL);           // 8320 floats
    unsigned int* counter = (unsigned int*)(partials + NTILES * 4);

    normalize_kernel<<<NROW / 4, 256, 0, stream>>>(hidden, xn, counter);
    pairloss_kernel<<<NTILES, 256, 0, stream>>>(xn, labels, partials, counter, out);
}

// Round 18
// 34.898 us; speedup vs baseline: 2.6878x; 2.6878x over previous
//
#include <hip/hip_runtime.h>
#include <hip/hip_bf16.h>
#include <hip/hip_fp8.h>

typedef float f32x16 __attribute__((ext_vector_type(16)));

constexpr int NROW = 8192;
constexpr int DCOL = 256;                  // row length in elements (= bytes in fp8)
constexpr int BM = 128;
constexpr int BKB = 128;                   // K-slab bytes (full 8-chunk swizzle period)
constexpr int NT = NROW / BM;              // 64
constexpr int NTILES = NT * (NT + 1) / 2;  // 2080 (divisible by 8)
constexpr float MARGIN = 0.3f;

// async global->LDS, 16B per lane; LDS dest is wave-uniform base (HW adds lane*16)
__device__ inline void gload16(const unsigned char* g, unsigned char* l) {
    __builtin_amdgcn_global_load_lds(
        (const __attribute__((address_space(1))) void*)g,
        (__attribute__((address_space(3))) void*)l, 16, 0, 0);
}

// ---------------- normalize rows -> fp8 e4m3 ----------------
__global__ __launch_bounds__(256) void normalize_kernel(const float* __restrict__ hidden,
                                                        unsigned char* __restrict__ xn) {
    int wid = threadIdx.x >> 6, lane = threadIdx.x & 63;
    int row = (blockIdx.x << 2) + wid;
    const float4* src = reinterpret_cast<const float4*>(hidden + (size_t)row * DCOL);
    float4 v = src[lane];
    float ss = v.x * v.x + v.y * v.y + v.z * v.z + v.w * v.w;
    #pragma unroll
    for (int off = 32; off; off >>= 1) ss += __shfl_down(ss, off);
    ss = __shfl(ss, 0);
    float inv = 1.0f / fmaxf(sqrtf(ss), 1e-8f);
    __hip_fp8_e4m3 q0(v.x * inv), q1(v.y * inv), q2(v.z * inv), q3(v.w * inv);
    uchar4 o;
    o.x = *reinterpret_cast<unsigned char*>(&q0);
    o.y = *reinterpret_cast<unsigned char*>(&q1);
    o.z = *reinterpret_cast<unsigned char*>(&q2);
    o.w = *reinterpret_cast<unsigned char*>(&q3);
    reinterpret_cast<uchar4*>(xn + (size_t)row * DCOL)[lane] = o;
}

// ---------------- 128x128-tile, 4-wave fp8 MFMA Gram + fused pair loss --------
// Measured best (r16, 34.2us total): single-slab LDS (34KB) -> 4 blocks/CU ->
// 4 waves/SIMD (VGPR-capped max). Serial 2-drain structure; drains and the
// ds_read->MFMA chain covered by 3 co-resident blocks' TLP. No shared-cacheline
// traffic in the hot path (r17 lesson: fused finalize cost 55us in serialization).
__global__ __launch_bounds__(256) void pairloss_kernel(const unsigned char* __restrict__ xn,
                                                       const int* __restrict__ labels,
                                                       float* __restrict__ partials) {
    __shared__ unsigned char As[BM * BKB];      // 16KB, one K-slab
    __shared__ unsigned char Bs[BM * BKB];      // 16KB
    __shared__ int lblA[BM], lblB[BM];
    __shared__ float wsum[4];

    // XCD-aware bijective swizzle
    int bid = (int)(blockIdx.x & 7) * (NTILES / 8) + (int)(blockIdx.x >> 3);
    int bi = 0, rem = bid;
    while (rem >= NT - bi) { rem -= NT - bi; ++bi; }
    int bj = bi + rem;

    int tid = threadIdx.x;
    int wid = tid >> 6, lane = tid & 63;
    int wr = wid >> 1, wc = wid & 1;            // 2x2 waves, wave tile 64x64
    int brow = bi * BM, bcol = bj * BM;

    if (tid < BM) lblA[tid] = labels[brow + tid];
    else          lblB[tid - BM] = labels[bcol + tid - BM];

    f32x16 acc[2][2] = {};                      // 2x2 tiles of 32x32 per wave

    int srow = lane >> 3;                       // row within 8-row group
    int schunk = (lane & 7) ^ srow;             // pre-swizzled 16B source chunk (r&7 == srow)
    const unsigned char* gA0 = xn + (size_t)brow * DCOL;
    const unsigned char* gB0 = xn + (size_t)bcol * DCOL;
    int lo = lane & 31, hi = lane >> 5;

    auto stage = [&](int s) {                   // 8 VMEM instr/thread per slab
        #pragma unroll
        for (int q = 0; q < 4; ++q) {
            int rg = (wid * 4 + q) * 8;         // wave-uniform 8-row group
            int goff = (rg + srow) * DCOL + s * BKB + schunk * 16;
            gload16(gA0 + goff, &As[rg * BKB]); // 8 rows x 128B, linear dest
            gload16(gB0 + goff, &Bs[rg * BKB]);
        }
    };
    auto compute = [&]() {
        #pragma unroll
        for (int kk = 0; kk < 8; ++kk) {        // K16 sub-steps of BKB=128
            long af[2], bfr[2];                 // 8 fp8 = 2 VGPRs each
            #pragma unroll
            for (int m = 0; m < 2; ++m) {
                int r = wr * 64 + m * 32 + lo;  // r&7 == lane&7
                af[m] = *reinterpret_cast<const long*>(
                    &As[r * BKB + ((kk ^ (r & 7)) << 4) + hi * 8]);
            }
            #pragma unroll
            for (int n = 0; n < 2; ++n) {
                int r = wc * 64 + n * 32 + lo;
                bfr[n] = *reinterpret_cast<const long*>(
                    &Bs[r * BKB + ((kk ^ (r & 7)) << 4) + hi * 8]);
            }
            __builtin_amdgcn_s_setprio(1);
            #pragma unroll
            for (int m = 0; m < 2; ++m)
                #pragma unroll
                for (int n = 0; n < 2; ++n)
                    acc[m][n] = __builtin_amdgcn_mfma_f32_32x32x16_fp8_fp8(af[m], bfr[n], acc[m][n], 0, 0, 0);
            __builtin_amdgcn_s_setprio(0);
        }
    };

    stage(0);
    asm volatile("s_waitcnt vmcnt(0)" ::: "memory");
    __builtin_amdgcn_s_barrier();               // slab0 landed for all waves
    compute();
    __builtin_amdgcn_s_barrier();               // all readers done before overwrite
    stage(1);
    asm volatile("s_waitcnt vmcnt(0)" ::: "memory");
    __builtin_amdgcn_s_barrier();               // slab1 landed
    compute();

    // epilogue: per-pair loss, strict upper triangle
    // 32x32 C/D: col = lane&31, row = (reg&3) + 8*(reg>>2) + 4*(lane>>5)  (dtype-independent)
    float local = 0.0f;
    #pragma unroll
    for (int m = 0; m < 2; ++m) {
        #pragma unroll
        for (int n = 0; n < 2; ++n) {
            #pragma unroll
            for (int g = 0; g < 16; ++g) {
                int crow = (g & 3) + 8 * (g >> 2) + 4 * hi;
                int il = wr * 64 + m * 32 + crow;
                int jl = wc * 64 + n * 32 + lo;
                int gi = brow + il, gj = bcol + jl;
                float sim = acc[m][n][g];
                float v = (lblA[il] == lblB[jl]) ? (1.0f - sim) : fmaxf(sim - MARGIN, 0.0f);
                local += (gi < gj) ? v : 0.0f;
            }
        }
    }
    #pragma unroll
    for (int off = 32; off; off >>= 1) local += __shfl_down(local, off);
    if (lane == 0) wsum[wid] = local;
    __syncthreads();
    if (tid == 0) partials[bid] = wsum[0] + wsum[1] + wsum[2] + wsum[3];
}

// ---------------- reduce partials -> loss ----------------
__global__ __launch_bounds__(256) void finalize_kernel(const float* __restrict__ partials,
                                                       float* __restrict__ out) {
    __shared__ float wsum[4];
    int tid = threadIdx.x, wid = tid >> 6, lane = tid & 63;
    float s = 0.0f;
    for (int i = tid; i < NTILES; i += 256) s += partials[i];
    #pragma unroll
    for (int off = 32; off; off >>= 1) s += __shfl_down(s, off);
    if (lane == 0) wsum[wid] = s;
    __syncthreads();
    if (tid == 0)
        out[0] = (wsum[0] + wsum[1] + wsum[2] + wsum[3]) * (1.0f / 33550336.0f);  // / (N*(N-1)/2)
}

extern "C" void kernel_launch(void* const* d_in, const int* in_sizes, int n_in,
                              void* d_out, int out_size, void* d_ws, size_t ws_size,
                              hipStream_t stream) {
    const float* hidden = (const float*)d_in[0];
    const int* labels = (const int*)d_in[1];
    float* out = (float*)d_out;

    unsigned char* xn = (unsigned char*)d_ws;                          // 2 MB fp8
    float* partials = (float*)((char*)d_ws + (size_t)NROW * DCOL);     // 2080 floats

    normalize_kernel<<<NROW / 4, 256, 0, stream>>>(hidden, xn);
    pairloss_kernel<<<NTILES, 256, 0, stream>>>(xn, labels, partials);
    finalize_kernel<<<1, 256, 0, stream>>>(partials, out);
}